// Round 1
// baseline (245.250 us; speedup 1.0000x reference)
//
#include <hip/hip_runtime.h>

// Problem constants (reference: B=4, L=8192, D=1024, K=7)
constexpr int B = 4;
constexpr int L = 8192;
constexpr int D = 1024;
constexpr int K = 7;
constexpr int HALF = K / 2;   // 3
constexpr int T = 64;         // l-positions per block (halo overhead 6/64 ~ 9%)

// One block: all D=1024 channels (256 threads x float4), T consecutive l.
// Causal depthwise conv: y[b,l,d] = bias[d] + sum_k w[d,k] * x[b, l+k-(K-1), d]
// Mask: count[b,l] = box7(boundaries), out = y * exp2(-count).
__global__ __launch_bounds__(256)
void dynconv_kernel(const float* __restrict__ x,
                    const float* __restrict__ sb,
                    const float* __restrict__ w,
                    const float* __restrict__ bias,
                    float* __restrict__ out)
{
    __shared__ float sh_mask[T];

    const int tile = blockIdx.x;            // 0 .. B*(L/T)-1
    const int b    = tile / (L / T);
    const int l0   = (tile % (L / T)) * T;
    const int tid  = threadIdx.x;

    // ---- per-tile mask precompute (one thread per l) ----
    if (tid < T) {
        const int l = l0 + tid;
        float cnt = 0.f;
        #pragma unroll
        for (int j = -HALF; j <= HALF; ++j) {
            const int p = l + j;
            if (p >= 0 && p < L) cnt += sb[(size_t)b * L + p];
        }
        sh_mask[tid] = exp2f(-cnt);         // 0.5 ** count (count is exact small int)
    }

    // ---- per-thread channel group: 4 channels, contiguous ----
    const int d0 = tid * 4;

    float wv[K][4];
    #pragma unroll
    for (int k = 0; k < K; ++k)
        #pragma unroll
        for (int c = 0; c < 4; ++c)
            wv[k][c] = w[(size_t)(d0 + c) * K + k];   // conv_w (D,1,K)

    const float4 bv = *(const float4*)(bias + d0);

    const float* xb = x   + (size_t)b * L * D + d0;
    float*       ob = out + ((size_t)b * L + (size_t)l0) * D + d0;

    // ---- sliding window prefill: win[j] = x[l0 - (K-1) + j], j = 0..K-2 ----
    float4 win[K];
    #pragma unroll
    for (int j = 0; j < K - 1; ++j) {
        const int l = l0 - (K - 1) + j;
        win[j] = (l >= 0) ? *(const float4*)(xb + (size_t)l * D)
                          : make_float4(0.f, 0.f, 0.f, 0.f);
    }

    __syncthreads();

    // ---- main loop over the l-tile, one load in flight ----
    float4 nxt = *(const float4*)(xb + (size_t)l0 * D);
    for (int t = 0; t < T; ++t) {
        win[K - 1] = nxt;
        if (t + 1 < T)
            nxt = *(const float4*)(xb + (size_t)(l0 + t + 1) * D);

        const float m = sh_mask[t];
        float4 acc = bv;
        #pragma unroll
        for (int k = 0; k < K; ++k) {
            acc.x += wv[k][0] * win[k].x;
            acc.y += wv[k][1] * win[k].y;
            acc.z += wv[k][2] * win[k].z;
            acc.w += wv[k][3] * win[k].w;
        }
        acc.x *= m; acc.y *= m; acc.z *= m; acc.w *= m;

        *(float4*)(ob + (size_t)t * D) = acc;

        #pragma unroll
        for (int j = 0; j < K - 1; ++j) win[j] = win[j + 1];
    }
}

extern "C" void kernel_launch(void* const* d_in, const int* in_sizes, int n_in,
                              void* d_out, int out_size, void* d_ws, size_t ws_size,
                              hipStream_t stream)
{
    const float* x    = (const float*)d_in[0];  // (B, L, D)
    const float* sb   = (const float*)d_in[1];  // (B, L)
    const float* w    = (const float*)d_in[2];  // (D, 1, K)
    const float* bias = (const float*)d_in[3];  // (D,)
    float* out = (float*)d_out;                 // (B, L, D)

    const int blocks = B * (L / T);             // 512
    dynconv_kernel<<<blocks, 256, 0, stream>>>(x, sb, w, bias, out);
}

// Round 3
// 237.107 us; speedup vs baseline: 1.0343x; 1.0343x over previous
//
#include <hip/hip_runtime.h>

// Problem constants (reference: B=4, L=8192, D=1024, K=7)
constexpr int B = 4;
constexpr int L = 8192;
constexpr int D = 1024;
constexpr int K = 7;
constexpr int HALF = K / 2;   // 3
constexpr int T = 8;          // l-positions per thread/block tile
constexpr int W = T + K - 1;  // 14 float4 window loads per thread

typedef float v4f __attribute__((ext_vector_type(4)));

// Block = 256 threads x v4f = all D=1024 channels, T consecutive l.
// All W window loads are issued up front (address-independent) -> 14 loads
// in flight per wave; single waitcnt drain; then compute T outputs + store.
__global__ __launch_bounds__(256, 4)
void dynconv_kernel(const float* __restrict__ x,
                    const float* __restrict__ sb,
                    const float* __restrict__ w,
                    const float* __restrict__ bias,
                    float* __restrict__ out)
{
    __shared__ float sh_mask[T];

    const int tile = blockIdx.x;            // 0 .. B*(L/T)-1
    const int nt   = L / T;                 // tiles per batch = 1024
    const int b    = tile / nt;
    const int l0   = (tile % nt) * T;
    const int tid  = threadIdx.x;

    // ---- per-tile mask (box-filter of boundaries, width 7) ----
    if (tid < T) {
        const int l = l0 + tid;
        float cnt = 0.f;
        #pragma unroll
        for (int j = -HALF; j <= HALF; ++j) {
            const int p = l + j;
            if (p >= 0 && p < L) cnt += sb[(size_t)b * L + p];
        }
        sh_mask[tid] = exp2f(-cnt);         // 0.5 ** count
    }

    const int d0 = tid * 4;

    // ---- window loads: x[b, l0-6 .. l0+T-1, d0:d0+4], all independent ----
    const float* xb = x + (size_t)b * L * D + d0;
    v4f X[W];
    #pragma unroll
    for (int j = 0; j < W; ++j) {
        const int l = l0 - (K - 1) + j;
        X[j] = (l >= 0) ? *(const v4f*)(xb + (size_t)l * D)
                        : (v4f)(0.f);
    }

    // ---- weights: 28 contiguous floats per thread (4 channels x K), as 7 v4f ----
    union { v4f q[7]; float f[28]; } wu;
    {
        const v4f* wp = (const v4f*)(w + (size_t)d0 * K); // 112B-aligned
        #pragma unroll
        for (int j = 0; j < 7; ++j) wu.q[j] = wp[j];
    }
    const v4f bv = *(const v4f*)(bias + d0);

    __syncthreads();

    float* ob = out + ((size_t)b * L + (size_t)l0) * D + d0;

    #pragma unroll
    for (int t = 0; t < T; ++t) {
        const float m = sh_mask[t];
        v4f acc = bv;
        #pragma unroll
        for (int k = 0; k < K; ++k) {
            // wv[k][c] = w[(d0+c)*K + k] = wu.f[c*7 + k]
            v4f wk = { wu.f[0 * K + k], wu.f[1 * K + k],
                       wu.f[2 * K + k], wu.f[3 * K + k] };
            acc += wk * X[t + k];
        }
        acc *= m;
        __builtin_nontemporal_store(acc, (v4f*)(ob + (size_t)t * D));
    }
}

extern "C" void kernel_launch(void* const* d_in, const int* in_sizes, int n_in,
                              void* d_out, int out_size, void* d_ws, size_t ws_size,
                              hipStream_t stream)
{
    const float* x    = (const float*)d_in[0];  // (B, L, D)
    const float* sb   = (const float*)d_in[1];  // (B, L)
    const float* w    = (const float*)d_in[2];  // (D, 1, K)
    const float* bias = (const float*)d_in[3];  // (D,)
    float* out = (float*)d_out;                 // (B, L, D)

    const int blocks = B * (L / T);             // 4096
    dynconv_kernel<<<blocks, 256, 0, stream>>>(x, sb, w, bias, out);
}